// Round 12
// baseline (145.842 us; speedup 1.0000x reference)
//
#include <hip/hip_runtime.h>
#include <math.h>

#define NB      8192
#define ND      2048
#define NC      100
#define NCP     112
#define ALPHA_  2.0f
#define MARGIN_ 0.05f

typedef short bf16x8 __attribute__((ext_vector_type(8)));
typedef float f32x4 __attribute__((ext_vector_type(4)));

static __device__ __forceinline__ unsigned short f2bf(float f) {
  unsigned u = __float_as_uint(f);
  u += 0x7FFFu + ((u >> 16) & 1u);
  return (unsigned short)(u >> 16);
}

// ACC float layout: [0,112) cls_ap | [112,114) sums(ce,ap) | [128,228) hist(int) | [240] done(int)

// ---- prepW: Wtf fragment-major bf16 (+ block 0 zeroes ACC strip) -----------
__global__ __launch_bounds__(256) void k_prepW(const float* __restrict__ W,
                                               unsigned short* __restrict__ Wtf,
                                               float* __restrict__ ACC) {
  const int t = threadIdx.x;
  if (blockIdx.x == 0) ACC[t] = 0.f;  // zeroes cls_ap, sums, hist, done
  const int f   = blockIdx.x * 256 + t;  // 0..28671
  const int ws  = f / 448;
  const int rem = f - ws * 448;
  const int i   = rem >> 6;
  const int l   = rem & 63;
  const int col = i * 16 + (l & 15);
  const int k0  = ws * 32 + (l >> 4) * 8;
  bf16x8 v;
#pragma unroll
  for (int j = 0; j < 8; ++j)
    v[j] = (short)((col < NC) ? f2bf(W[(size_t)(k0 + j) * NC + col]) : 0);
  *(bf16x8*)(Wtf + (size_t)f * 8) = v;
}

// ---- prepG: G2 = W^T W, pa2 = A @ W (112x112 tiles via MFMA) ---------------
__global__ __launch_bounds__(512) void k_prepG(const unsigned short* __restrict__ Wtf,
                                               const float* __restrict__ A,
                                               float* __restrict__ G2,
                                               float* __restrict__ pa2) {
  __shared__ float red[8][8][64];
  const int t    = threadIdx.x;
  const int w    = t >> 6;
  const int lane = t & 63;
  const int ti   = blockIdx.x / 7;
  const int tj   = blockIdx.x % 7;
  const int arow = ti * 16 + (lane & 15);

  f32x4 accG = {0.f, 0.f, 0.f, 0.f};
  f32x4 accP = {0.f, 0.f, 0.f, 0.f};
#pragma unroll
  for (int s = 0; s < 8; ++s) {
    const int ws = w * 8 + s;
    const bf16x8 afr = *(const bf16x8*)(Wtf + (size_t)(ws * 7 + ti) * 512 + lane * 8);
    const bf16x8 bfr = *(const bf16x8*)(Wtf + (size_t)(ws * 7 + tj) * 512 + lane * 8);
    accG = __builtin_amdgcn_mfma_f32_16x16x32_bf16(afr, bfr, accG, 0, 0, 0);
    bf16x8 aa;
    if (arow < NC) {
      const float* __restrict__ ar =
          A + (size_t)arow * ND + ws * 32 + (lane >> 4) * 8;
      const float4 v0 = *(const float4*)(ar);
      const float4 v1 = *(const float4*)(ar + 4);
      aa[0] = (short)f2bf(v0.x); aa[1] = (short)f2bf(v0.y);
      aa[2] = (short)f2bf(v0.z); aa[3] = (short)f2bf(v0.w);
      aa[4] = (short)f2bf(v1.x); aa[5] = (short)f2bf(v1.y);
      aa[6] = (short)f2bf(v1.z); aa[7] = (short)f2bf(v1.w);
    } else {
#pragma unroll
      for (int q = 0; q < 8; ++q) aa[q] = 0;
    }
    accP = __builtin_amdgcn_mfma_f32_16x16x32_bf16(aa, bfr, accP, 0, 0, 0);
  }
#pragma unroll
  for (int rg = 0; rg < 4; ++rg) {
    red[w][rg][lane]     = accG[rg];
    red[w][4 + rg][lane] = accP[rg];
  }
  __syncthreads();
  if (w < 2) {
    const int vb = w * 4;
    float* __restrict__ dst = (w == 0) ? G2 : pa2;
#pragma unroll
    for (int rg = 0; rg < 4; ++rg) {
      float s = 0.f;
#pragma unroll
      for (int w2 = 0; w2 < 8; ++w2) s += red[w2][vb + rg][lane];
      const int row = ti * 16 + (lane >> 4) * 4 + rg;
      dst[row * NCP + tj * 16 + (lane & 15)] = s;
    }
  }
}

// ---- prep2: T=softmax(pa)-I ; Ut + label histogram -------------------------
__global__ __launch_bounds__(128) void k_prep2(const float* __restrict__ G2,
                                               const float* __restrict__ pa2,
                                               const int* __restrict__ Y,
                                               float* __restrict__ Ut,
                                               int* __restrict__ hist) {
  __shared__ float vals[128];
  __shared__ float tl[128];
  const int cp = blockIdx.x;
  const int t  = threadIdx.x;
  {  // histogram slice: 82 entries per block
    const int i = cp * 82 + t;
    if (t < 82 && i < NB) atomicAdd(&hist[Y[i]], 1);
  }
  const float v = (t < NC) ? pa2[cp * NCP + t] : -INFINITY;
  vals[t] = v;
  __syncthreads();
  float m = -INFINITY;
  for (int c = 0; c < NC; ++c) m = fmaxf(m, vals[c]);
  float se = 0.f;
  for (int c = 0; c < NC; ++c) se += __expf(vals[c] - m);
  tl[t] = (t < NC) ? (__expf(v - m) / se - (t == cp ? 1.f : 0.f)) : 0.f;
  __syncthreads();
  if (t < NC) {
    float u = 0.f;
    for (int c = 0; c < NC; ++c) u = fmaf(G2[c * NCP + t], tl[c], u);
    Ut[cp * NC + t] = u;
  }
}

// ---- main: r10 body + fused tail via last-block-done pattern ---------------
__global__ __launch_bounds__(512, 4) void k_main(const float* __restrict__ X,
                                                 const unsigned short* __restrict__ Wtf,
                                                 const int* __restrict__ Y,
                                                 const float* __restrict__ Ut,
                                                 float* __restrict__ S_part,
                                                 float* __restrict__ ACC,
                                                 float* __restrict__ out) {
  __shared__ __align__(16) char smem[65536];  // 8 x 8KB wave slabs; reused
  __shared__ bool lastFlag;
  float* __restrict__ cls_ap = ACC;
  float* __restrict__ sums   = ACC + 112;
  const int* __restrict__ hist = (const int*)ACC + 128;
  int* __restrict__ done       = (int*)ACC + 240;

  const int t    = threadIdx.x;
  const int w    = t >> 6;     // wave 0..7 = K-slice (256 K each)
  const int lane = t & 63;
  const int row0 = blockIdx.x * 16;
  char* __restrict__ wbase = smem + w * 8192;

  // issue first B-fragment batch BEFORE the X stage (independent of LDS)
  const unsigned short* __restrict__ bp0 =
      Wtf + (size_t)(w * 8 * 7) * 512 + lane * 8;
  bf16x8 cur[7], nxt[7];
#pragma unroll
  for (int i = 0; i < 7; ++i) cur[i] = *(const bf16x8*)(bp0 + i * 512);

  // ---- per-wave stage: 16 rows x 256 K, f32 -> bf16, XOR-swizzled [row][k] --
  {
    const int srow = lane >> 2;
    const int sc   = lane & 3;
    const float* __restrict__ xr =
        X + (size_t)(row0 + srow) * ND + w * 256 + sc * 8;
    const int wsz = (srow & 7) << 4;
#pragma unroll
    for (int j = 0; j < 8; ++j) {
      const float4 v0 = *(const float4*)(xr + j * 32);
      const float4 v1 = *(const float4*)(xr + j * 32 + 4);
      bf16x8 p;
      p[0] = (short)f2bf(v0.x); p[1] = (short)f2bf(v0.y);
      p[2] = (short)f2bf(v0.z); p[3] = (short)f2bf(v0.w);
      p[4] = (short)f2bf(v1.x); p[5] = (short)f2bf(v1.y);
      p[6] = (short)f2bf(v1.z); p[7] = (short)f2bf(v1.w);
      *(bf16x8*)(wbase + srow * 512 + ((sc * 16 + j * 64) ^ wsz)) = p;
    }
  }
  // no barrier: slab is wave-private (ds_write->ds_read ordered in-wave)

  const int r = lane & 15;
  const int g = lane >> 4;

  f32x4 acc[7];
  const f32x4 z = {0.f, 0.f, 0.f, 0.f};
#pragma unroll
  for (int i = 0; i < 7; ++i) acc[i] = z;

  const char* __restrict__ abase = wbase + r * 512;
  const int asz = (r & 7) << 4;
#pragma unroll
  for (int s = 0; s < 8; ++s) {
    const bf16x8 xf = *(const bf16x8*)(abase + ((s * 64 + g * 16) ^ asz));
    if (s < 7) {
      const unsigned short* __restrict__ bpn = bp0 + (size_t)(s + 1) * 7 * 512;
#pragma unroll
      for (int i = 0; i < 7; ++i) nxt[i] = *(const bf16x8*)(bpn + i * 512);
    }
#pragma unroll
    for (int i = 0; i < 7; ++i)
      acc[i] = __builtin_amdgcn_mfma_f32_16x16x32_bf16(xf, cur[i], acc[i], 0, 0, 0);
#pragma unroll
    for (int i = 0; i < 7; ++i) cur[i] = nxt[i];
  }
  __syncthreads();  // all waves done with slabs -> reuse for reduction

  float* __restrict__ redp = (float*)smem;            // [8][7][4][64] = 57344 B
  float* __restrict__ sp   = (float*)(smem + 57344);  // [112] + ce + ap
#pragma unroll
  for (int i = 0; i < 7; ++i)
#pragma unroll
    for (int j = 0; j < 4; ++j)
      redp[(w * 7 + i) * 256 + j * 64 + lane] = acc[i][j];
  if (t < NCP + 2) sp[t] = 0.f;
  __syncthreads();

  // epilogue: waves 0..3 each own j = w (rows g*4 + j)
  if (w < 4) {
    const int j = w;
    float v[7];
#pragma unroll
    for (int i = 0; i < 7; ++i) {
      float s = 0.f;
#pragma unroll
      for (int w2 = 0; w2 < 8; ++w2)
        s += redp[(w2 * 7 + i) * 256 + j * 64 + lane];
      v[i] = s;
    }
    const bool v6  = (96 + r) < NC;
    const int  row = row0 + g * 4 + j;
    const int  yr  = Y[row];

    float m = -INFINITY;
#pragma unroll
    for (int i = 0; i < 6; ++i) m = fmaxf(m, v[i]);
    if (v6) m = fmaxf(m, v[6]);
#pragma unroll
    for (int off = 8; off > 0; off >>= 1) m = fmaxf(m, __shfl_xor(m, off));

    float e[7];
    float se = 0.f, py = 0.f;
#pragma unroll
    for (int i = 0; i < 7; ++i) {
      const bool valid = (i < 6) | v6;
      e[i] = valid ? __expf(v[i] - m) : 0.f;
      se += e[i];
      if (i * 16 + r == yr) py = v[i];
    }
#pragma unroll
    for (int off = 8; off > 0; off >>= 1) {
      se += __shfl_xor(se, off);
      py += __shfl_xor(py, off);
    }
    const float ce  = m + __logf(se) - py;
    const float inv = 1.f / se;

    const float* __restrict__ uty = Ut + yr * NC;
    float ap = 0.f;
    float s[7];
#pragma unroll
    for (int i = 0; i < 7; ++i) {
      const int col = i * 16 + r;
      s[i] = e[i] * inv - (col == yr ? 1.f : 0.f);
      const float u = ((i < 6) | v6) ? uty[col] : 0.f;
      ap = fmaf(s[i], u, ap);
    }
#pragma unroll
    for (int off = 8; off > 0; off >>= 1) ap += __shfl_xor(ap, off);

    if (r == 0) {
      atomicAdd(&sp[NCP], ce);
      atomicAdd(&sp[NCP + 1], ap);
      atomicAdd(&cls_ap[yr], ap);   // 16 global atomics / block
    }
#pragma unroll
    for (int i = 0; i < 7; ++i) atomicAdd(&sp[i * 16 + r], s[i]);
  }
  __syncthreads();
  if (t < NCP) S_part[(size_t)t * 512 + blockIdx.x] = sp[t];  // column-major
  if (t == NCP) atomicAdd(&sums[0], sp[NCP]);
  if (t == NCP + 1) atomicAdd(&sums[1], sp[NCP + 1]);

  // ---- last-block-done: final reduction + loss ----
  __threadfence();
  __syncthreads();
  if (t == 0) lastFlag = (atomicAdd(done, 1) == 511);
  __syncthreads();
  if (!lastFlag) return;
  __threadfence();

  float* __restrict__ stot = (float*)smem;           // 112 floats
  float* __restrict__ red2 = (float*)(smem + 2048);  // 512 floats
  for (int c = w; c < NCP; c += 8) {
    float s = 0.f;
#pragma unroll
    for (int q = 0; q < 8; ++q) s += S_part[(size_t)c * 512 + q * 64 + lane];
#pragma unroll
    for (int off = 32; off > 0; off >>= 1) s += __shfl_xor(s, off);
    if (lane == 0) stot[c] = s;
  }
  __syncthreads();
  float part = 0.f;
  if (t < NC) {
    float dot = 0.f;
    for (int c = 0; c < NC; ++c) dot = fmaf(stot[c], Ut[t * NC + c], dot);
    part = (float)hist[t] * (dot - cls_ap[t]);
  }
  red2[t] = part;
  __syncthreads();
  for (int off = 256; off > 0; off >>= 1) {
    if (t < off) red2[t] += red2[t + off];
    __syncthreads();
  }
  if (t == 0) {
    out[0] = (sums[0] + ALPHA_ * (red2[0] - sums[1] + (float)NB * MARGIN_)) /
             (float)NB;
  }
}

extern "C" void kernel_launch(void* const* d_in, const int* in_sizes, int n_in,
                              void* d_out, int out_size, void* d_ws,
                              size_t ws_size, hipStream_t stream) {
  const float* X = (const float*)d_in[0];
  const float* W = (const float*)d_in[1];
  const float* A = (const float*)d_in[2];
  const int*   Y = (const int*)d_in[3];
  float* out = (float*)d_out;
  char*  ws  = (char*)d_ws;

  float*          G2     = (float*)(ws + 0);       // 50176 B
  float*          pa2    = (float*)(ws + 50176);   // 50176 B
  float*          Ut     = (float*)(ws + 100352);  // 40000 B
  float*          ACC    = (float*)(ws + 140800);  // 1024 B (zeroed in prepW)
  unsigned short* Wtf    = (unsigned short*)(ws + 147456);  // 458752 B
  float*          S_part = (float*)(ws + 606208);  // 112*512*4 = 229376 B

  k_prepW<<<112, 256, 0, stream>>>(W, Wtf, ACC);
  k_prepG<<<49, 512, 0, stream>>>(Wtf, A, G2, pa2);
  k_prep2<<<NC, 128, 0, stream>>>(G2, pa2, Y, Ut, (int*)ACC + 128);
  k_main<<<NB / 16, 512, 0, stream>>>(X, Wtf, Y, Ut, S_part, ACC, out);
}

// Round 13
// 75.940 us; speedup vs baseline: 1.9205x; 1.9205x over previous
//
#include <hip/hip_runtime.h>
#include <math.h>

#define NB      8192
#define ND      2048
#define NC      100
#define NCP     112
#define ALPHA_  2.0f
#define MARGIN_ 0.05f

typedef short bf16x8 __attribute__((ext_vector_type(8)));
typedef float f32x4 __attribute__((ext_vector_type(4)));

static __device__ __forceinline__ unsigned short f2bf(float f) {
  unsigned u = __float_as_uint(f);
  u += 0x7FFFu + ((u >> 16) & 1u);
  return (unsigned short)(u >> 16);
}
static __device__ __forceinline__ bf16x8 pack8(const float4 a, const float4 b) {
  bf16x8 p;
  p[0] = (short)f2bf(a.x); p[1] = (short)f2bf(a.y);
  p[2] = (short)f2bf(a.z); p[3] = (short)f2bf(a.w);
  p[4] = (short)f2bf(b.x); p[5] = (short)f2bf(b.y);
  p[6] = (short)f2bf(b.z); p[7] = (short)f2bf(b.w);
  return p;
}

// ACC floats: [0,896) S_rep[8][112] | [896,996) cls_ap | [996,998) sums(ce,ap)
//             | [1024,1124) hist(int)   — zeroed by prepW block 0

// ---- prepW: Wtf fragment-major bf16 (+ block 0 zeroes ACC) -----------------
__global__ __launch_bounds__(256) void k_prepW(const float* __restrict__ W,
                                               unsigned short* __restrict__ Wtf,
                                               float* __restrict__ ACC) {
  const int t = threadIdx.x;
  if (blockIdx.x == 0)
    for (int i = t; i < 1152; i += 256) ACC[i] = 0.f;
  const int f   = blockIdx.x * 256 + t;  // 0..28671
  const int ws  = f / 448;
  const int rem = f - ws * 448;
  const int i   = rem >> 6;
  const int l   = rem & 63;
  const int col = i * 16 + (l & 15);
  const int k0  = ws * 32 + (l >> 4) * 8;
  bf16x8 v;
#pragma unroll
  for (int j = 0; j < 8; ++j)
    v[j] = (short)((col < NC) ? f2bf(W[(size_t)(k0 + j) * NC + col]) : 0);
  *(bf16x8*)(Wtf + (size_t)f * 8) = v;
}

// ---- prepG: G2 = W^T W, pa2 = A @ W (112x112 tiles via MFMA) ---------------
__global__ __launch_bounds__(512) void k_prepG(const unsigned short* __restrict__ Wtf,
                                               const float* __restrict__ A,
                                               float* __restrict__ G2,
                                               float* __restrict__ pa2) {
  __shared__ float red[8][8][64];
  const int t    = threadIdx.x;
  const int w    = t >> 6;
  const int lane = t & 63;
  const int ti   = blockIdx.x / 7;
  const int tj   = blockIdx.x % 7;
  const int arow = ti * 16 + (lane & 15);

  f32x4 accG = {0.f, 0.f, 0.f, 0.f};
  f32x4 accP = {0.f, 0.f, 0.f, 0.f};
#pragma unroll
  for (int s = 0; s < 8; ++s) {
    const int ws = w * 8 + s;
    const bf16x8 afr = *(const bf16x8*)(Wtf + (size_t)(ws * 7 + ti) * 512 + lane * 8);
    const bf16x8 bfr = *(const bf16x8*)(Wtf + (size_t)(ws * 7 + tj) * 512 + lane * 8);
    accG = __builtin_amdgcn_mfma_f32_16x16x32_bf16(afr, bfr, accG, 0, 0, 0);
    bf16x8 aa;
    if (arow < NC) {
      const float* __restrict__ ar =
          A + (size_t)arow * ND + ws * 32 + (lane >> 4) * 8;
      const float4 v0 = *(const float4*)(ar);
      const float4 v1 = *(const float4*)(ar + 4);
      aa = pack8(v0, v1);
    } else {
#pragma unroll
      for (int q = 0; q < 8; ++q) aa[q] = 0;
    }
    accP = __builtin_amdgcn_mfma_f32_16x16x32_bf16(aa, bfr, accP, 0, 0, 0);
  }
#pragma unroll
  for (int rg = 0; rg < 4; ++rg) {
    red[w][rg][lane]     = accG[rg];
    red[w][4 + rg][lane] = accP[rg];
  }
  __syncthreads();
  if (w < 2) {
    const int vb = w * 4;
    float* __restrict__ dst = (w == 0) ? G2 : pa2;
#pragma unroll
    for (int rg = 0; rg < 4; ++rg) {
      float s = 0.f;
#pragma unroll
      for (int w2 = 0; w2 < 8; ++w2) s += red[w2][vb + rg][lane];
      const int row = ti * 16 + (lane >> 4) * 4 + rg;
      dst[row * NCP + tj * 16 + (lane & 15)] = s;
    }
  }
}

// ---- prep2: Ut + label histogram -------------------------------------------
__global__ __launch_bounds__(128) void k_prep2(const float* __restrict__ G2,
                                               const float* __restrict__ pa2,
                                               const int* __restrict__ Y,
                                               float* __restrict__ Ut,
                                               int* __restrict__ hist) {
  __shared__ float vals[128];
  __shared__ float tl[128];
  const int cp = blockIdx.x;
  const int t  = threadIdx.x;
  {
    const int i = cp * 82 + t;
    if (t < 82 && i < NB) atomicAdd(&hist[Y[i]], 1);
  }
  const float v = (t < NC) ? pa2[cp * NCP + t] : -INFINITY;
  vals[t] = v;
  __syncthreads();
  float m = -INFINITY;
  for (int c = 0; c < NC; ++c) m = fmaxf(m, vals[c]);
  float se = 0.f;
  for (int c = 0; c < NC; ++c) se += __expf(vals[c] - m);
  tl[t] = (t < NC) ? (__expf(v - m) / se - (t == cp ? 1.f : 0.f)) : 0.f;
  __syncthreads();
  if (t < NC) {
    float u = 0.f;
    for (int c = 0; c < NC; ++c) u = fmaf(G2[c * NCP + t], tl[c], u);
    Ut[cp * NC + t] = u;
  }
}

// ---- main: pure GEMM. 32 rows x K-half per block, X direct from global. ----
// grid 512 = 256 row-tiles x 2 K-halves; 8 waves each own K-slice 128.
// Each B-fragment feeds 2 MFMAs (rows 0-15 / 16-31): B L2 traffic halved.
__global__ __launch_bounds__(512, 4) void k_main(const float* __restrict__ X,
                                                 const unsigned short* __restrict__ Wtf,
                                                 float* __restrict__ px2) {
  __shared__ __align__(16) float redp[14336];  // [8][7][4][64] = 57344 B
  const int t    = threadIdx.x;
  const int w    = t >> 6;
  const int lane = t & 63;
  const int r    = lane & 15;
  const int g    = lane >> 4;
  const int kh   = blockIdx.x & 1;
  const int row0 = (blockIdx.x >> 1) * 32;

  f32x4 acc[7][2];
  const f32x4 z = {0.f, 0.f, 0.f, 0.f};
#pragma unroll
  for (int i = 0; i < 7; ++i) { acc[i][0] = z; acc[i][1] = z; }

  const int kbase = kh * 1024 + w * 128;
  const float* __restrict__ xp0 = X + (size_t)(row0 + r) * ND + kbase + g * 8;
  const float* __restrict__ xp1 = xp0 + (size_t)16 * ND;
  const unsigned short* __restrict__ bp0 =
      Wtf + (size_t)((kh * 32 + w * 4) * 7) * 512 + lane * 8;

#pragma unroll
  for (int s = 0; s < 4; ++s) {
    const float4 a00 = *(const float4*)(xp0 + s * 32);
    const float4 a01 = *(const float4*)(xp0 + s * 32 + 4);
    const float4 a10 = *(const float4*)(xp1 + s * 32);
    const float4 a11 = *(const float4*)(xp1 + s * 32 + 4);
    const unsigned short* __restrict__ bp = bp0 + (size_t)s * 7 * 512;
    bf16x8 bf[7];
#pragma unroll
    for (int i = 0; i < 7; ++i) bf[i] = *(const bf16x8*)(bp + i * 512);
    const bf16x8 xf0 = pack8(a00, a01);
    const bf16x8 xf1 = pack8(a10, a11);
#pragma unroll
    for (int i = 0; i < 7; ++i) {
      acc[i][0] = __builtin_amdgcn_mfma_f32_16x16x32_bf16(xf0, bf[i], acc[i][0], 0, 0, 0);
      acc[i][1] = __builtin_amdgcn_mfma_f32_16x16x32_bf16(xf1, bf[i], acc[i][1], 0, 0, 0);
    }
  }

  // two-pass cross-wave reduce (8 K-slices) -> px2 partial store
#pragma unroll
  for (int h = 0; h < 2; ++h) {
    if (h) __syncthreads();
#pragma unroll
    for (int i = 0; i < 7; ++i)
#pragma unroll
      for (int j = 0; j < 4; ++j)
        redp[(w * 7 + i) * 256 + j * 64 + lane] = acc[i][h][j];
    __syncthreads();
    if (w < 4) {
      const int j   = w;
      const int row = row0 + h * 16 + g * 4 + j;
      float* __restrict__ dst =
          px2 + (size_t)(kh * NB + row) * NCP + r;
#pragma unroll
      for (int i = 0; i < 7; ++i) {
        float s = 0.f;
#pragma unroll
        for (int w2 = 0; w2 < 8; ++w2)
          s += redp[(w2 * 7 + i) * 256 + j * 64 + lane];
        dst[i * 16] = s;
      }
    }
  }
}

// ---- epi: softmax/ce/ap/stats from px2 (64 blocks, low-contention tail) ----
__global__ __launch_bounds__(512) void k_epi(const float* __restrict__ px2,
                                             const int* __restrict__ Y,
                                             const float* __restrict__ Ut,
                                             float* __restrict__ ACC) {
  __shared__ float sp[224];  // [0,112) S cols | [112,212) clsap | 212 ce | 213 ap
  const int t    = threadIdx.x;
  const int w    = t >> 6;
  const int lane = t & 63;
  const int r    = lane & 15;
  const int g    = lane >> 4;
  if (t < 224) sp[t] = 0.f;
  __syncthreads();

  const bool v6 = (96 + r) < NC;
#pragma unroll
  for (int j = 0; j < 4; ++j) {
    const int row = blockIdx.x * 128 + w * 16 + g * 4 + j;
    const int yr  = Y[row];
    const float* __restrict__ p0 = px2 + (size_t)row * NCP + r;
    const float* __restrict__ p1 = p0 + (size_t)NB * NCP;
    float v[7];
#pragma unroll
    for (int i = 0; i < 7; ++i) v[i] = p0[i * 16] + p1[i * 16];

    float m = -INFINITY;
#pragma unroll
    for (int i = 0; i < 6; ++i) m = fmaxf(m, v[i]);
    if (v6) m = fmaxf(m, v[6]);
#pragma unroll
    for (int off = 8; off > 0; off >>= 1) m = fmaxf(m, __shfl_xor(m, off));

    float e[7];
    float se = 0.f, py = 0.f;
#pragma unroll
    for (int i = 0; i < 7; ++i) {
      const bool valid = (i < 6) | v6;
      e[i] = valid ? __expf(v[i] - m) : 0.f;
      se += e[i];
      if (i * 16 + r == yr) py = v[i];
    }
#pragma unroll
    for (int off = 8; off > 0; off >>= 1) {
      se += __shfl_xor(se, off);
      py += __shfl_xor(py, off);
    }
    const float ce  = m + __logf(se) - py;
    const float inv = 1.f / se;

    const float* __restrict__ uty = Ut + yr * NC;
    float ap = 0.f;
    float s[7];
#pragma unroll
    for (int i = 0; i < 7; ++i) {
      const int col = i * 16 + r;
      s[i] = e[i] * inv - (col == yr ? 1.f : 0.f);
      const float u = ((i < 6) | v6) ? uty[col] : 0.f;
      ap = fmaf(s[i], u, ap);
    }
#pragma unroll
    for (int off = 8; off > 0; off >>= 1) ap += __shfl_xor(ap, off);

    if (r == 0) {
      atomicAdd(&sp[212], ce);
      atomicAdd(&sp[213], ap);
      atomicAdd(&sp[112 + yr], ap);
    }
#pragma unroll
    for (int i = 0; i < 7; ++i) atomicAdd(&sp[i * 16 + r], s[i]);
  }
  __syncthreads();
  if (t < NCP) atomicAdd(&ACC[(blockIdx.x & 7) * NCP + t], sp[t]);
  else if (t < 212) atomicAdd(&ACC[896 + (t - 112)], sp[t]);
  else if (t < 214) atomicAdd(&ACC[996 + (t - 212)], sp[t]);
}

// ---- final: stot, dot, loss ------------------------------------------------
__global__ __launch_bounds__(128) void k_final(const float* __restrict__ ACC,
                                               const float* __restrict__ Ut,
                                               float* __restrict__ out) {
  __shared__ float stot[NCP];
  __shared__ float red2[128];
  const int t = threadIdx.x;
  const int* __restrict__ hist = (const int*)ACC + 1024;
  if (t < NCP) {
    float s = 0.f;
#pragma unroll
    for (int rep = 0; rep < 8; ++rep) s += ACC[rep * NCP + t];
    stot[t] = s;
  }
  __syncthreads();
  float part = 0.f;
  if (t < NC) {
    float dot = 0.f;
    for (int c = 0; c < NC; ++c) dot = fmaf(stot[c], Ut[t * NC + c], dot);
    part = (float)hist[t] * (dot - ACC[896 + t]);
  }
  red2[t] = part;
  __syncthreads();
  for (int off = 64; off > 0; off >>= 1) {
    if (t < off) red2[t] += red2[t + off];
    __syncthreads();
  }
  if (t == 0) {
    const float ce = ACC[996];
    const float ap = ACC[997];
    out[0] = (ce + ALPHA_ * (red2[0] - ap + (float)NB * MARGIN_)) / (float)NB;
  }
}

extern "C" void kernel_launch(void* const* d_in, const int* in_sizes, int n_in,
                              void* d_out, int out_size, void* d_ws,
                              size_t ws_size, hipStream_t stream) {
  const float* X = (const float*)d_in[0];
  const float* W = (const float*)d_in[1];
  const float* A = (const float*)d_in[2];
  const int*   Y = (const int*)d_in[3];
  float* out = (float*)d_out;
  char*  ws  = (char*)d_ws;

  float*          G2  = (float*)(ws + 0);       // 50176 B
  float*          pa2 = (float*)(ws + 50176);   // 50176 B
  float*          Ut  = (float*)(ws + 100352);  // 40000 B
  float*          ACC = (float*)(ws + 140800);  // 4608 B (zeroed in prepW)
  unsigned short* Wtf = (unsigned short*)(ws + 147456);  // 458752 B
  float*          px2 = (float*)(ws + 606208);  // 2*8192*112*4 = 7340032 B

  k_prepW<<<112, 256, 0, stream>>>(W, Wtf, ACC);
  k_prepG<<<49, 512, 0, stream>>>(Wtf, A, G2, pa2);
  k_prep2<<<NC, 128, 0, stream>>>(G2, pa2, Y, Ut, (int*)ACC + 1024);
  k_main<<<512, 512, 0, stream>>>(X, Wtf, px2);
  k_epi<<<64, 512, 0, stream>>>(px2, Y, Ut, ACC);
  k_final<<<1, 128, 0, stream>>>(ACC, Ut, out);
}